// Round 11
// baseline (225.065 us; speedup 1.0000x reference)
//
#include <hip/hip_runtime.h>
#include <hip/hip_bf16.h>

// R16: attn as BARRIER-FREE SINGLE-WAVE blocks. Cycle model showed R14-attn
// is latency-bound (VALU 12.8us / LDS 12us / MFMA 6.8us of pipe work in a
// 41us kernel) with occupancy grid-capped at 4 coupled blocks/CU. Now:
// 64-thread blocks (1 wave = 32 q), KVBLK=32, grid 4096 (16b x 16qt x 16h).
// LDS 9.7KB/block -> 16 independent waves/CU; barriers gate only their own
// wave (near-free). Staging stays coalesced-row LDS (R12 falsified scattered
// gathers, not staging). LDTV=40 verified conflict-free both phases.
// prep/proj unchanged (R15 forms).

typedef __bf16 bf16;
typedef bf16 bf16x8 __attribute__((ext_vector_type(8)));
typedef bf16 bf16x4 __attribute__((ext_vector_type(4)));
typedef float floatx4 __attribute__((ext_vector_type(4)));
typedef float floatx16 __attribute__((ext_vector_type(16)));
typedef unsigned short ushort8 __attribute__((ext_vector_type(8)));
typedef unsigned long long u64;

#define MFMA32(A, B, C)    __builtin_amdgcn_mfma_f32_16x16x32_bf16((A), (B), (C), 0, 0, 0)
#define MFMA32x32(A, B, C) __builtin_amdgcn_mfma_f32_32x32x16_bf16((A), (B), (C), 0, 0, 0)

namespace {
constexpr int S    = 512;
constexpr int H    = 16;
constexpr int Dh   = 64;
constexpr int D    = 1024;
constexpr int LDT  = 72;                         // K-tile row stride (bf16)
constexpr int LDTV = 40;                         // V-tile row stride (bf16), 32+8 pad
constexpr size_t QN = (size_t)16 * S * H * Dh;   // 8,388,608
constexpr size_t WN = (size_t)D * D;             // 1,048,576
}

__device__ __forceinline__ float fexp2(float x) {
#if defined(__HIP_DEVICE_COMPILE__) && __has_builtin(__builtin_amdgcn_exp2f)
    return __builtin_amdgcn_exp2f(x);
#else
    return exp2f(x);
#endif
}

__device__ __forceinline__ int sbfe1(unsigned bits, int bit) {
    return ((int)(bits << (31 - bit))) >> 31;    // folds to v_bfe_i32
}

// Async global->LDS, 16B per lane. lds base must be wave-uniform (HW adds lane*16).
__device__ __forceinline__ void gload16(const bf16* g, bf16* ldsbase, int lane) {
#if __has_builtin(__builtin_amdgcn_global_load_lds)
    __builtin_amdgcn_global_load_lds(
        (__attribute__((address_space(1))) void*)(g),
        (__attribute__((address_space(3))) void*)(ldsbase), 16, 0, 0);
#else
    *(ushort8*)(ldsbase + lane * 8) = *(const ushort8*)g;   // host-pass / fallback
#endif
}

// Fused prep, grid 4352:
// [0,1024) K f32->bf16 x4 chunks | [1024,3072) V transpose | [3072,3328) W
// transpose | [3328,4352) mask bit-pack x4 units.
__global__ __launch_bounds__(256)
void prep_kernel(const float* __restrict__ Kf, const float* __restrict__ Vf,
                 const float* __restrict__ Wf, const int* __restrict__ Mg,
                 bf16* __restrict__ Kc, bf16* __restrict__ Vt,
                 bf16* __restrict__ Wt, u64* __restrict__ MB)
{
    __shared__ bf16 Ts[64 * LDT];
    const int blk = blockIdx.x, tid = threadIdx.x;

    if (blk < 1024) {                       // ---- K convert, 4 chunks/thread ----
        const int c0 = blk * 1024 + tid;    // chunk ids c0 + 256*k
        floatx4 f[4][2];
#pragma unroll
        for (int k = 0; k < 4; ++k) {
            const float* fs = Kf + (size_t)(c0 + k * 256) * 8;
            f[k][0] = *(const floatx4*)fs;
            f[k][1] = *(const floatx4*)(fs + 4);
        }
#pragma unroll
        for (int k = 0; k < 4; ++k) {
            bf16x8 v;
#pragma unroll
            for (int j = 0; j < 4; ++j) {
                v[j]     = (bf16)f[k][0][j];
                v[j + 4] = (bf16)f[k][1][j];
            }
            *(bf16x8*)(Kc + (size_t)(c0 + k * 256) * 8) = v;
        }
    } else if (blk < 3072) {                // ---- V [b][s][h][d] -> [(bh)][d][s] ----
        const int bk2 = blk - 1024;
        const int bh  = bk2 >> 3, st = bk2 & 7;
        const int b   = bh >> 4, h = bh & 15;
        const int r   = tid >> 2, c = (tid & 3) * 16;
        const float* src = Vf + ((size_t)((b * S + st * 64 + r) * H + h)) * Dh + c;
        floatx4 f0 = *(const floatx4*)src;          // vectorized: 4x dwordx4
        floatx4 f1 = *(const floatx4*)(src + 4);
        floatx4 f2 = *(const floatx4*)(src + 8);
        floatx4 f3 = *(const floatx4*)(src + 12);
        // element (d,s) stored at d*LDT + (s ^ (d&48)): write conflicts 8->2-way
#pragma unroll
        for (int i = 0; i < 4; ++i) {
            Ts[(c + i)      * LDT + (r ^ ((c + i)      & 48))] = (bf16)f0[i];
            Ts[(c + 4 + i)  * LDT + (r ^ ((c + 4 + i)  & 48))] = (bf16)f1[i];
            Ts[(c + 8 + i)  * LDT + (r ^ ((c + 8 + i)  & 48))] = (bf16)f2[i];
            Ts[(c + 12 + i) * LDT + (r ^ ((c + 12 + i) & 48))] = (bf16)f3[i];
        }
        __syncthreads();
        bf16* dst = Vt + ((size_t)bh * 64 + r) * S + st * 64 + c;
        const int rb = r * LDT + (c ^ (r & 48));
        *(ushort8*)dst       = *(const ushort8*)&Ts[rb];
        *(ushort8*)(dst + 8) = *(const ushort8*)&Ts[rb + 8];
    } else if (blk < 3328) {                // ---- W [k][n] -> [n][k] ----
        const int bk2 = blk - 3072;
        const int nb  = bk2 & 15, kb = bk2 >> 4;
        const int r   = tid >> 2, c = (tid & 3) * 16;
        const float* src = Wf + (size_t)(kb * 64 + r) * D + nb * 64 + c;
        floatx4 f0 = *(const floatx4*)src;          // vectorized: 4x dwordx4
        floatx4 f1 = *(const floatx4*)(src + 4);
        floatx4 f2 = *(const floatx4*)(src + 8);
        floatx4 f3 = *(const floatx4*)(src + 12);
#pragma unroll
        for (int i = 0; i < 4; ++i) {
            Ts[(c + i)      * LDT + (r ^ ((c + i)      & 48))] = (bf16)f0[i];
            Ts[(c + 4 + i)  * LDT + (r ^ ((c + 4 + i)  & 48))] = (bf16)f1[i];
            Ts[(c + 8 + i)  * LDT + (r ^ ((c + 8 + i)  & 48))] = (bf16)f2[i];
            Ts[(c + 12 + i) * LDT + (r ^ ((c + 12 + i) & 48))] = (bf16)f3[i];
        }
        __syncthreads();
        bf16* dst = Wt + (size_t)(nb * 64 + r) * D + kb * 64 + c;
        const int rb = r * LDT + (c ^ (r & 48));
        *(ushort8*)dst       = *(const ushort8*)&Ts[rb];
        *(ushort8*)(dst + 8) = *(const ushort8*)&Ts[rb + 8];
    } else {                                // ---- mask -> u64 bitmask, 4 units/wave ----
        const int bk2  = blk - 3328;        // [0,1024)
        const int lane = tid & 63;
        const int wv   = tid >> 6;
        const int u0   = bk2 * 16 + wv * 4; // idx4 base
        int mv[4][4];
#pragma unroll
        for (int u = 0; u < 4; ++u) {
            const int idx4 = u0 + u;
            const int row = idx4 >> 1, hf = idx4 & 1;
#pragma unroll
            for (int r = 0; r < 4; ++r)
                mv[u][r] = Mg[(size_t)row * 512 + hf * 256 + r * 64 + lane];
        }
#pragma unroll
        for (int u = 0; u < 4; ++u) {
            const int idx4 = u0 + u;
            const int row = idx4 >> 1, hf = idx4 & 1;
#pragma unroll
            for (int r = 0; r < 4; ++r) {
                u64 bm = __ballot(mv[u][r] != 0);
                if (lane == 0) MB[(size_t)row * 8 + hf * 4 + r] = bm;
            }
        }
    }
}

// One workgroup = ONE WAVE = one (b, h, 32-row q-tile). q = qt*32 + l31.
// KVBLK=32: 16 iterations; LDS 9.7KB -> 16 independent blocks/CU, barriers
// gate only this wave. S^T/PV on mfma_f32_32x32x16_bf16;
// C/D: col=lane&31, row=(reg&3)+8*(reg>>2)+4*half.
__global__ __launch_bounds__(64, 4)
void attn_kernel(const float* __restrict__ Qg, const bf16* __restrict__ Kc,
                 const bf16* __restrict__ Vtg, const u64* __restrict__ MB,
                 bf16* __restrict__ heads)
{
    __shared__ bf16 Ks[32 * LDT];                 // k-rows permuted (swap bits 2<->3)
    __shared__ bf16 Vs[64 * LDTV];                // [d][s-in-tile], natural order

    const int lane = threadIdx.x & 63;
    const int l31  = lane & 31;
    const int half = lane >> 5;

    const int blk = blockIdx.x;                   // ((b*16)+qt)*16 + h
    const int h   = blk & 15;
    const int qt  = (blk >> 4) & 15;
    const int b   = blk >> 8;
    const int qw  = qt * 32;                      // q = qw + l31

    // ---- Q B-frags: lane holds Q[qw+l31][ds*16 + half*8 + j] * 0.125*log2e ----
    constexpr float QSCL = 0.125f * 1.44269504088896340736f;
    bf16x8 aq[4];
    {
        const float* qb = Qg + ((size_t)((b * S + qw + l31) * H + h)) * Dh + half * 8;
#pragma unroll
        for (int ds = 0; ds < 4; ++ds) {
            floatx4 f0 = *(const floatx4*)(qb + ds * 16);
            floatx4 f1 = *(const floatx4*)(qb + ds * 16 + 4);
#pragma unroll
            for (int j = 0; j < 4; ++j) {
                aq[ds][j]     = (bf16)(f0[j] * QSCL);
                aq[ds][j + 4] = (bf16)(f1[j] * QSCL);
            }
        }
    }

    float rsum = 0.f;
    floatx16 O[2];                                // O^T[d = dt*32 + crow][q = l31]
#pragma unroll
    for (int dt = 0; dt < 2; ++dt)
#pragma unroll
        for (int i = 0; i < 16; ++i) O[dt][i] = 0.f;

    const u64* mbrow = MB + ((size_t)b * S + qw + l31) * 8;   // per-lane q row
    const bf16* vplane = Vtg + (size_t)(b * 16 + h) * 64 * S;

    // K staging: 2 lanes/row over 32 rows, 32 cols each; row permuted
    // (swap bits 2<->3) so S^T C-tile lands P^T in B-operand order.
    const int kr = lane >> 1, kc = (lane & 1) * 32;
    const int kp = (kr & 0x13) | ((kr & 4) << 1) | ((kr & 8) >> 1);
    // V staging: 4 lanes/row over 16 rows x 4 passes, 8 cols each.
    const int vr = lane >> 2, vc = (lane & 3) * 8;

    for (int it = 0; it < 16; ++it) {
        const int kb = it * 32;
        const bf16* ksrc = Kc + ((size_t)((b * S + kb + kp) * H + h)) * Dh + kc;
        ushort8 k0 = *(const ushort8*)ksrc;
        ushort8 k1 = *(const ushort8*)(ksrc + 8);
        ushort8 k2 = *(const ushort8*)(ksrc + 16);
        ushort8 k3 = *(const ushort8*)(ksrc + 24);
        ushort8 v0 = *(const ushort8*)(vplane + (size_t)vr        * S + kb + vc);
        ushort8 v1 = *(const ushort8*)(vplane + (size_t)(vr + 16) * S + kb + vc);
        ushort8 v2 = *(const ushort8*)(vplane + (size_t)(vr + 32) * S + kb + vc);
        ushort8 v3 = *(const ushort8*)(vplane + (size_t)(vr + 48) * S + kb + vc);
        const u64 m64 = mbrow[it >> 1];           // covers k bits [ (it>>1)*64, +64 )

        __syncthreads();                          // 1-wave barrier: near-free
        *(ushort8*)&Ks[kr * LDT + kc]        = k0;
        *(ushort8*)&Ks[kr * LDT + kc + 8]    = k1;
        *(ushort8*)&Ks[kr * LDT + kc + 16]   = k2;
        *(ushort8*)&Ks[kr * LDT + kc + 24]   = k3;
        *(ushort8*)&Vs[vr * LDTV + vc]        = v0;
        *(ushort8*)&Vs[(vr + 16) * LDTV + vc] = v1;
        *(ushort8*)&Vs[(vr + 32) * LDTV + vc] = v2;
        *(ushort8*)&Vs[(vr + 48) * LDTV + vc] = v3;
        __syncthreads();

        // ---- S^T: C reg r holds k = kb + (r>>3)*16 + half*8 + (r&7) ----
        floatx16 acc;
#pragma unroll
        for (int i = 0; i < 16; ++i) acc[i] = 0.f;
#pragma unroll
        for (int ds = 0; ds < 4; ++ds) {
            bf16x8 ak = *(const bf16x8*)&Ks[l31 * LDT + ds * 16 + half * 8];
            acc = MFMA32x32(ak, aq[ds], acc);
        }
        const unsigned w = (unsigned)(m64 >> ((it & 1) * 32 + half * 8));
        bf16x8 pB[2];                             // P^T B-operands, 16-k slice each
#pragma unroll
        for (int r = 0; r < 16; ++r) {
            float e = fexp2(acc[r]);                    // v_exp_f32
            int sx = sbfe1(w, (r >> 3) * 16 + (r & 7)); // 0 or -1
            float p = __uint_as_float(__float_as_uint(e) & (unsigned)sx);
            rsum += p;
            pB[r >> 3][r & 7] = (bf16)p;
        }

        // ---- O^T += V^T · P^T : A = Vs rows (natural), B = pB k-slices ----
#pragma unroll
        for (int dt = 0; dt < 2; ++dt)
#pragma unroll
            for (int s_ = 0; s_ < 2; ++s_) {
                bf16x8 av = *(const bf16x8*)&Vs[(dt * 32 + l31) * LDTV + s_ * 16 + half * 8];
                O[dt] = MFMA32x32(av, pB[s_], O[dt]);
            }
    }

    // ---- reduce row sums: lanes l and l+32 share q = l31, disjoint k halves ----
    rsum += __shfl_xor(rsum, 32, 64);
    const float inv = (rsum > 0.f) ? (1.f / rsum) : 0.f;

    // ---- epilogue: O^T[d][q] -> heads[b][q][h][d]; d = dt*32 + g*8 + half*4 + j ----
    bf16* hrow = heads + ((size_t)((b * S + qw + l31) * H + h)) * Dh;
#pragma unroll
    for (int dt = 0; dt < 2; ++dt) {
#pragma unroll
        for (int g = 0; g < 4; ++g) {
            bf16x4 h4;
#pragma unroll
            for (int j = 0; j < 4; ++j) h4[j] = (bf16)(O[dt][g * 4 + j] * inv);
            *(bf16x4*)&hrow[dt * 32 + g * 8 + half * 4] = h4;
        }
    }
}

// Projection: heads (8192x1024) @ Wt^T. m97 structure: 128x128 tile, BK=32,
// LINEAR LDS, global_load_lds width=16, 2 barriers per K-step.
__global__ __launch_bounds__(256)
void proj_kernel(const bf16* __restrict__ A, const bf16* __restrict__ Wt,
                 float* __restrict__ out)
{
    __shared__ bf16 As[128 * 32];                 // linear, 8 KB
    __shared__ bf16 Ws[128 * 32];                 // linear, 8 KB

    const int tid  = threadIdx.x;
    const int lane = tid & 63;
    const int wave = tid >> 6;
    const int l15  = lane & 15;
    const int quad = lane >> 4;

    const int nb = blockIdx.x & 7;
    const int mb = blockIdx.x >> 3;
    const int mbase = mb * 128, nbase = nb * 128;
    const int wm = (wave & 1) * 64, wn = (wave >> 1) * 64;

    // staging: wave handles chunks {2w, 2w+1}; chunk = 16 rows x 32 cols (1 KB)
    const int ch0  = wave * 2;
    const int srow = lane >> 2;                   // 0..15 within chunk
    const int scol = (lane & 3) * 8;              // bf16 col

    floatx4 O[4][4];
#pragma unroll
    for (int mt = 0; mt < 4; ++mt)
#pragma unroll
        for (int nt = 0; nt < 4; ++nt) O[mt][nt] = floatx4{0.f, 0.f, 0.f, 0.f};

    for (int kt = 0; kt < 32; ++kt) {
        const int kb = kt * 32;
        if (kt) __syncthreads();                  // prev compute done; LDS free

        gload16(A  + (size_t)(mbase + ch0 * 16      + srow) * D + kb + scol, As + ch0 * 512,       lane);
        gload16(A  + (size_t)(mbase + (ch0 + 1) * 16 + srow) * D + kb + scol, As + (ch0 + 1) * 512, lane);
        gload16(Wt + (size_t)(nbase + ch0 * 16      + srow) * D + kb + scol, Ws + ch0 * 512,       lane);
        gload16(Wt + (size_t)(nbase + (ch0 + 1) * 16 + srow) * D + kb + scol, Ws + (ch0 + 1) * 512, lane);

        __syncthreads();                          // vmcnt drained -> LDS visible

        bf16x8 fa[4];
#pragma unroll
        for (int mt = 0; mt < 4; ++mt)
            fa[mt] = *(const bf16x8*)&As[(wm + mt * 16 + l15) * 32 + quad * 8];
#pragma unroll
        for (int nt = 0; nt < 4; ++nt) {
            bf16x8 fb = *(const bf16x8*)&Ws[(wn + nt * 16 + l15) * 32 + quad * 8];
#pragma unroll
            for (int mt = 0; mt < 4; ++mt)
                O[mt][nt] = MFMA32(fa[mt], fb, O[mt][nt]);
        }
    }

#pragma unroll
    for (int mt = 0; mt < 4; ++mt) {
#pragma unroll
        for (int nt = 0; nt < 4; ++nt) {
#pragma unroll
            for (int reg = 0; reg < 4; ++reg) {
                const int m = mbase + wm + mt * 16 + quad * 4 + reg;
                const int n = nbase + wn + nt * 16 + l15;
                out[(size_t)m * D + n] = O[mt][nt][reg];
            }
        }
    }
}

extern "C" void kernel_launch(void* const* d_in, const int* in_sizes, int n_in,
                              void* d_out, int out_size, void* d_ws, size_t ws_size,
                              hipStream_t stream)
{
    const float* pre_q = (const float*)d_in[0];
    const float* pre_v = (const float*)d_in[1];
    const float* pre_k = (const float*)d_in[2];
    const int*   mask  = (const int*)d_in[3];
    const float* Wg    = (const float*)d_in[4];
    float* out = (float*)d_out;

    bf16* Kc    = (bf16*)d_ws;
    bf16* Vt    = Kc + QN;
    bf16* Wt    = Vt + QN;
    bf16* heads = Wt + WN;
    u64*  MB    = (u64*)(heads + QN);

    prep_kernel<<<4352, 256, 0, stream>>>(pre_k, pre_v, Wg, mask, Kc, Vt, Wt, MB);
    attn_kernel<<<4096, 64, 0, stream>>>(pre_q, Kc, Vt, MB, heads);
    proj_kernel<<<512, 256, 0, stream>>>(heads, Wt, out);
}

// Round 12
// 206.350 us; speedup vs baseline: 1.0907x; 1.0907x over previous
//
#include <hip/hip_runtime.h>
#include <hip/hip_bf16.h>

// R17:
//  attn: exact R11 form (KVBLK=64, single buffer, 0 conflicts) -- six
//    restructures (R7/R10/R12/R13/R14/R16) failed to beat it; frozen.
//  proj: BK 32->64 (barrier/vmcnt-drain events 32->16) + XOR swizzle done
//    rule-21-correct: LDS linear for global_load_lds, GLOBAL source column
//    pre-swizzled (cu = (lane&7)^(lane>>3)), reads re-apply the XOR
//    (cu' = (quad+4kh)^(row&7)). Kills the derived 8-way read conflict of
//    the old [128][32] layout (bank = 16*l15+4*quad -> 2 groups/16 lanes).
//  prep: R15 form (vectorized transpose loads).

typedef __bf16 bf16;
typedef bf16 bf16x8 __attribute__((ext_vector_type(8)));
typedef bf16 bf16x4 __attribute__((ext_vector_type(4)));
typedef float floatx4 __attribute__((ext_vector_type(4)));
typedef float floatx16 __attribute__((ext_vector_type(16)));
typedef unsigned short ushort8 __attribute__((ext_vector_type(8)));
typedef unsigned long long u64;

#define MFMA32(A, B, C)    __builtin_amdgcn_mfma_f32_16x16x32_bf16((A), (B), (C), 0, 0, 0)
#define MFMA32x32(A, B, C) __builtin_amdgcn_mfma_f32_32x32x16_bf16((A), (B), (C), 0, 0, 0)

namespace {
constexpr int S   = 512;
constexpr int H   = 16;
constexpr int Dh  = 64;
constexpr int D   = 1024;
constexpr int LDT = 72;                          // padded LDS row stride (bf16)
constexpr size_t QN = (size_t)16 * S * H * Dh;   // 8,388,608
constexpr size_t WN = (size_t)D * D;             // 1,048,576
}

__device__ __forceinline__ float fexp2(float x) {
#if defined(__HIP_DEVICE_COMPILE__) && __has_builtin(__builtin_amdgcn_exp2f)
    return __builtin_amdgcn_exp2f(x);
#else
    return exp2f(x);
#endif
}

__device__ __forceinline__ int sbfe1(unsigned bits, int bit) {
    return ((int)(bits << (31 - bit))) >> 31;    // folds to v_bfe_i32
}

// Async global->LDS, 16B per lane. lds base must be wave-uniform (HW adds lane*16).
__device__ __forceinline__ void gload16(const bf16* g, bf16* ldsbase, int lane) {
#if __has_builtin(__builtin_amdgcn_global_load_lds)
    __builtin_amdgcn_global_load_lds(
        (__attribute__((address_space(1))) void*)(g),
        (__attribute__((address_space(3))) void*)(ldsbase), 16, 0, 0);
#else
    *(ushort8*)(ldsbase + lane * 8) = *(const ushort8*)g;   // host-pass / fallback
#endif
}

// Fused prep, grid 4352:
// [0,1024) K f32->bf16 x4 chunks | [1024,3072) V transpose | [3072,3328) W
// transpose | [3328,4352) mask bit-pack x4 units.
__global__ __launch_bounds__(256)
void prep_kernel(const float* __restrict__ Kf, const float* __restrict__ Vf,
                 const float* __restrict__ Wf, const int* __restrict__ Mg,
                 bf16* __restrict__ Kc, bf16* __restrict__ Vt,
                 bf16* __restrict__ Wt, u64* __restrict__ MB)
{
    __shared__ bf16 Ts[64 * LDT];
    const int blk = blockIdx.x, tid = threadIdx.x;

    if (blk < 1024) {                       // ---- K convert, 4 chunks/thread ----
        const int c0 = blk * 1024 + tid;    // chunk ids c0 + 256*k
        floatx4 f[4][2];
#pragma unroll
        for (int k = 0; k < 4; ++k) {
            const float* fs = Kf + (size_t)(c0 + k * 256) * 8;
            f[k][0] = *(const floatx4*)fs;
            f[k][1] = *(const floatx4*)(fs + 4);
        }
#pragma unroll
        for (int k = 0; k < 4; ++k) {
            bf16x8 v;
#pragma unroll
            for (int j = 0; j < 4; ++j) {
                v[j]     = (bf16)f[k][0][j];
                v[j + 4] = (bf16)f[k][1][j];
            }
            *(bf16x8*)(Kc + (size_t)(c0 + k * 256) * 8) = v;
        }
    } else if (blk < 3072) {                // ---- V [b][s][h][d] -> [(bh)][d][s] ----
        const int bk2 = blk - 1024;
        const int bh  = bk2 >> 3, st = bk2 & 7;
        const int b   = bh >> 4, h = bh & 15;
        const int r   = tid >> 2, c = (tid & 3) * 16;
        const float* src = Vf + ((size_t)((b * S + st * 64 + r) * H + h)) * Dh + c;
        floatx4 f0 = *(const floatx4*)src;          // vectorized: 4x dwordx4
        floatx4 f1 = *(const floatx4*)(src + 4);
        floatx4 f2 = *(const floatx4*)(src + 8);
        floatx4 f3 = *(const floatx4*)(src + 12);
        // element (d,s) stored at d*LDT + (s ^ (d&48)): write conflicts 8->2-way
#pragma unroll
        for (int i = 0; i < 4; ++i) {
            Ts[(c + i)      * LDT + (r ^ ((c + i)      & 48))] = (bf16)f0[i];
            Ts[(c + 4 + i)  * LDT + (r ^ ((c + 4 + i)  & 48))] = (bf16)f1[i];
            Ts[(c + 8 + i)  * LDT + (r ^ ((c + 8 + i)  & 48))] = (bf16)f2[i];
            Ts[(c + 12 + i) * LDT + (r ^ ((c + 12 + i) & 48))] = (bf16)f3[i];
        }
        __syncthreads();
        bf16* dst = Vt + ((size_t)bh * 64 + r) * S + st * 64 + c;
        const int rb = r * LDT + (c ^ (r & 48));
        *(ushort8*)dst       = *(const ushort8*)&Ts[rb];
        *(ushort8*)(dst + 8) = *(const ushort8*)&Ts[rb + 8];
    } else if (blk < 3328) {                // ---- W [k][n] -> [n][k] ----
        const int bk2 = blk - 3072;
        const int nb  = bk2 & 15, kb = bk2 >> 4;
        const int r   = tid >> 2, c = (tid & 3) * 16;
        const float* src = Wf + (size_t)(kb * 64 + r) * D + nb * 64 + c;
        floatx4 f0 = *(const floatx4*)src;          // vectorized: 4x dwordx4
        floatx4 f1 = *(const floatx4*)(src + 4);
        floatx4 f2 = *(const floatx4*)(src + 8);
        floatx4 f3 = *(const floatx4*)(src + 12);
#pragma unroll
        for (int i = 0; i < 4; ++i) {
            Ts[(c + i)      * LDT + (r ^ ((c + i)      & 48))] = (bf16)f0[i];
            Ts[(c + 4 + i)  * LDT + (r ^ ((c + 4 + i)  & 48))] = (bf16)f1[i];
            Ts[(c + 8 + i)  * LDT + (r ^ ((c + 8 + i)  & 48))] = (bf16)f2[i];
            Ts[(c + 12 + i) * LDT + (r ^ ((c + 12 + i) & 48))] = (bf16)f3[i];
        }
        __syncthreads();
        bf16* dst = Wt + (size_t)(nb * 64 + r) * D + kb * 64 + c;
        const int rb = r * LDT + (c ^ (r & 48));
        *(ushort8*)dst       = *(const ushort8*)&Ts[rb];
        *(ushort8*)(dst + 8) = *(const ushort8*)&Ts[rb + 8];
    } else {                                // ---- mask -> u64 bitmask, 4 units/wave ----
        const int bk2  = blk - 3328;        // [0,1024)
        const int lane = tid & 63;
        const int wv   = tid >> 6;
        const int u0   = bk2 * 16 + wv * 4; // idx4 base
        int mv[4][4];
#pragma unroll
        for (int u = 0; u < 4; ++u) {
            const int idx4 = u0 + u;
            const int row = idx4 >> 1, hf = idx4 & 1;
#pragma unroll
            for (int r = 0; r < 4; ++r)
                mv[u][r] = Mg[(size_t)row * 512 + hf * 256 + r * 64 + lane];
        }
#pragma unroll
        for (int u = 0; u < 4; ++u) {
            const int idx4 = u0 + u;
            const int row = idx4 >> 1, hf = idx4 & 1;
#pragma unroll
            for (int r = 0; r < 4; ++r) {
                u64 bm = __ballot(mv[u][r] != 0);
                if (lane == 0) MB[(size_t)row * 8 + hf * 4 + r] = bm;
            }
        }
    }
}

// One workgroup = one (b, h, 128-row q-tile). 4 waves x 32 q each (q = qw + l31).
// S^T and PV on mfma_f32_32x32x16_bf16; C/D: col=lane&31, row=(reg&3)+8*(reg>>2)+4*half.
__global__ __launch_bounds__(256, 4)
void attn_kernel(const float* __restrict__ Qg, const bf16* __restrict__ Kc,
                 const bf16* __restrict__ Vtg, const u64* __restrict__ MB,
                 bf16* __restrict__ heads)
{
    __shared__ bf16 Ks[64 * LDT];                 // rows PERMUTED: slot r = k-row swap23(r)
    __shared__ bf16 Vt[64 * LDT];                 // [d][s-in-tile], natural order

    const int tid  = threadIdx.x;
    const int lane = tid & 63;
    const int wave = tid >> 6;
    const int l31  = lane & 31;
    const int half = lane >> 5;

    const int blk = blockIdx.x;                   // ((b*4)+qt)*16 + h
    const int h   = blk & 15;
    const int qt  = (blk >> 4) & 3;
    const int b   = blk >> 6;
    const int qw  = qt * 128 + wave * 32;         // wave's q base; q = qw + l31

    // ---- Q B-frags: lane holds Q[qw+l31][ds*16 + half*8 + j] * 0.125*log2e ----
    constexpr float QSCL = 0.125f * 1.44269504088896340736f;
    bf16x8 aq[4];
    {
        const float* qb = Qg + ((size_t)((b * S + qw + l31) * H + h)) * Dh + half * 8;
#pragma unroll
        for (int ds = 0; ds < 4; ++ds) {
            floatx4 f0 = *(const floatx4*)(qb + ds * 16);
            floatx4 f1 = *(const floatx4*)(qb + ds * 16 + 4);
#pragma unroll
            for (int j = 0; j < 4; ++j) {
                aq[ds][j]     = (bf16)(f0[j] * QSCL);
                aq[ds][j + 4] = (bf16)(f1[j] * QSCL);
            }
        }
    }

    float rsum = 0.f;
    floatx16 O[2];                                // O^T[d = dt*32 + crow][q = l31]
#pragma unroll
    for (int dt = 0; dt < 2; ++dt)
#pragma unroll
        for (int i = 0; i < 16; ++i) O[dt][i] = 0.f;

    const u64* mbrow = MB + ((size_t)b * S + qw + l31) * 8;   // per-lane q row
    const bf16* vplane = Vtg + (size_t)(b * 16 + h) * 64 * S;

    const int sr = tid >> 2, sc_ = (tid & 3) * 16;            // 64x64 staging
    // swap bits 2<->3: staging slot r holds global k-row kperm so the S^T
    // C-tile lands P^T in 32x32x16 B-operand order (slot s*8+j <-> C reg s*8+j).
    const int kperm = (sr & 0x33) | ((sr & 4) << 1) | ((sr & 8) >> 1);

    for (int kt = 0; kt < 8; ++kt) {
        const int kb = kt * 64;
        const bf16* ksrc = Kc + ((size_t)((b * S + kb + kperm) * H + h)) * Dh + sc_;
        const bf16* vsrc = vplane + (size_t)sr * S + kb + sc_;
        ushort8 k0 = *(const ushort8*)ksrc;
        ushort8 k1 = *(const ushort8*)(ksrc + 8);
        ushort8 v0 = *(const ushort8*)vsrc;
        ushort8 v1 = *(const ushort8*)(vsrc + 8);
        u64 m64 = mbrow[kt];                      // bit k of this lane's q row

        __syncthreads();                          // prev tile's LDS reads done
        *(ushort8*)&Ks[sr * LDT + sc_]     = k0;
        *(ushort8*)&Ks[sr * LDT + sc_ + 8] = k1;
        *(ushort8*)&Vt[sr * LDT + sc_]     = v0;
        *(ushort8*)&Vt[sr * LDT + sc_ + 8] = v1;
        __syncthreads();

        // ---- S^T per 32-k tile t: C reg r holds k = t*32 + (r>>3)*16 + half*8 + (r&7) ----
        bf16x8 pB[4];                             // P^T B-operands, 16-k slice each
#pragma unroll
        for (int t = 0; t < 2; ++t) {
            floatx16 acc;
#pragma unroll
            for (int i = 0; i < 16; ++i) acc[i] = 0.f;
#pragma unroll
            for (int ds = 0; ds < 4; ++ds) {
                bf16x8 ak = *(const bf16x8*)&Ks[(t * 32 + l31) * LDT + ds * 16 + half * 8];
                acc = MFMA32x32(ak, aq[ds], acc);
            }
            const unsigned w = (unsigned)(m64 >> (t * 32 + half * 8));
#pragma unroll
            for (int r = 0; r < 16; ++r) {
                float e = fexp2(acc[r]);                    // v_exp_f32
                int sx = sbfe1(w, (r >> 3) * 16 + (r & 7)); // 0 or -1
                float p = __uint_as_float(__float_as_uint(e) & (unsigned)sx);
                rsum += p;
                pB[t * 2 + (r >> 3)][r & 7] = (bf16)p;
            }
        }

        // ---- O^T += V^T · P^T : A = Vt rows (natural), B = pB k-slices ----
#pragma unroll
        for (int dt = 0; dt < 2; ++dt)
#pragma unroll
            for (int s_ = 0; s_ < 4; ++s_) {
                bf16x8 av = *(const bf16x8*)&Vt[(dt * 32 + l31) * LDT + s_ * 16 + half * 8];
                O[dt] = MFMA32x32(av, pB[s_], O[dt]);
            }
    }

    // ---- reduce row sums: lanes l and l+32 share q = l31, disjoint k halves ----
    rsum += __shfl_xor(rsum, 32, 64);
    const float inv = (rsum > 0.f) ? (1.f / rsum) : 0.f;

    // ---- epilogue: O^T[d][q] -> heads[b][q][h][d]; d = dt*32 + g*8 + half*4 + j ----
    bf16* hrow = heads + ((size_t)((b * S + qw + l31) * H + h)) * Dh;
#pragma unroll
    for (int dt = 0; dt < 2; ++dt) {
#pragma unroll
        for (int g = 0; g < 4; ++g) {
            bf16x4 h4;
#pragma unroll
            for (int j = 0; j < 4; ++j) h4[j] = (bf16)(O[dt][g * 4 + j] * inv);
            *(bf16x4*)&hrow[dt * 32 + g * 8 + half * 4] = h4;
        }
    }
}

// Projection: heads (8192x1024) @ Wt^T. 128x128 tile, BK=64, LDS linear for
// global_load_lds with PRE-SWIZZLED global source (rule 21): 16B unit at
// logical (row, cu) lives at physical cu' = cu ^ (row&7). Reads re-apply the
// XOR -> conflict-free (8 rows cover 8 bank-quads). 16 K-steps (drains halved).
__global__ __launch_bounds__(256)
void proj_kernel(const bf16* __restrict__ A, const bf16* __restrict__ Wt,
                 float* __restrict__ out)
{
    __shared__ bf16 As[128 * 64];                 // 16 KB, linear
    __shared__ bf16 Ws[128 * 64];                 // 16 KB, linear

    const int tid  = threadIdx.x;
    const int lane = tid & 63;
    const int wave = tid >> 6;
    const int l15  = lane & 15;
    const int quad = lane >> 4;

    const int nb = blockIdx.x & 7;
    const int mb = blockIdx.x >> 3;
    const int mbase = mb * 128, nbase = nb * 128;
    const int wm = (wave & 1) * 64, wn = (wave >> 1) * 64;

    // staging: per wave-issue j, rows rowbase..rowbase+8; lane covers
    // (row = rowbase + (lane>>3), col 16B-unit cu = (lane&7) ^ (lane>>3)).
    // Since rowbase % 8 == 0, (row&7) == lane>>3 -> source col pre-swizzled.
    const int srow = lane >> 3;                       // 0..7
    const int scsw = ((lane & 7) ^ (lane >> 3)) * 8;  // swizzled col (bf16)

    floatx4 O[4][4];
#pragma unroll
    for (int mt = 0; mt < 4; ++mt)
#pragma unroll
        for (int nt = 0; nt < 4; ++nt) O[mt][nt] = floatx4{0.f, 0.f, 0.f, 0.f};

    for (int kt = 0; kt < 16; ++kt) {
        const int kb = kt * 64;
        if (kt) __syncthreads();                  // prev compute done; LDS free

#pragma unroll
        for (int j = 0; j < 4; ++j) {
            const int rowbase = j * 32 + wave * 8;
            gload16(A  + (size_t)(mbase + rowbase + srow) * D + kb + scsw,
                    As + rowbase * 64, lane);
            gload16(Wt + (size_t)(nbase + rowbase + srow) * D + kb + scsw,
                    Ws + rowbase * 64, lane);
        }

        __syncthreads();                          // vmcnt drained -> LDS visible

        bf16x8 fa[4][2];
#pragma unroll
        for (int mt = 0; mt < 4; ++mt) {
            const int row = wm + mt * 16 + l15;
            const int sw  = row & 7;
            fa[mt][0] = *(const bf16x8*)&As[row * 64 + ((quad ^ sw) * 8)];
            fa[mt][1] = *(const bf16x8*)&As[row * 64 + (((quad + 4) ^ sw) * 8)];
        }
#pragma unroll
        for (int nt = 0; nt < 4; ++nt) {
            const int row = wn + nt * 16 + l15;
            const int sw  = row & 7;
            bf16x8 fb0 = *(const bf16x8*)&Ws[row * 64 + ((quad ^ sw) * 8)];
            bf16x8 fb1 = *(const bf16x8*)&Ws[row * 64 + (((quad + 4) ^ sw) * 8)];
#pragma unroll
            for (int mt = 0; mt < 4; ++mt) {
                O[mt][nt] = MFMA32(fa[mt][0], fb0, O[mt][nt]);
                O[mt][nt] = MFMA32(fa[mt][1], fb1, O[mt][nt]);
            }
        }
    }

#pragma unroll
    for (int mt = 0; mt < 4; ++mt) {
#pragma unroll
        for (int nt = 0; nt < 4; ++nt) {
#pragma unroll
            for (int reg = 0; reg < 4; ++reg) {
                const int m = mbase + wm + mt * 16 + quad * 4 + reg;
                const int n = nbase + wn + nt * 16 + l15;
                out[(size_t)m * D + n] = O[mt][nt][reg];
            }
        }
    }
}

extern "C" void kernel_launch(void* const* d_in, const int* in_sizes, int n_in,
                              void* d_out, int out_size, void* d_ws, size_t ws_size,
                              hipStream_t stream)
{
    const float* pre_q = (const float*)d_in[0];
    const float* pre_v = (const float*)d_in[1];
    const float* pre_k = (const float*)d_in[2];
    const int*   mask  = (const int*)d_in[3];
    const float* Wg    = (const float*)d_in[4];
    float* out = (float*)d_out;

    bf16* Kc    = (bf16*)d_ws;
    bf16* Vt    = Kc + QN;
    bf16* Wt    = Vt + QN;
    bf16* heads = Wt + WN;
    u64*  MB    = (u64*)(heads + QN);

    prep_kernel<<<4352, 256, 0, stream>>>(pre_k, pre_v, Wg, mask, Kc, Vt, Wt, MB);
    attn_kernel<<<1024, 256, 0, stream>>>(pre_q, Kc, Vt, MB, heads);
    proj_kernel<<<512, 256, 0, stream>>>(heads, Wt, out);
}

// Round 13
// 203.809 us; speedup vs baseline: 1.1043x; 1.0125x over previous
//
#include <hip/hip_runtime.h>
#include <hip/hip_bf16.h>

// R18:
//  attn: UNCONDITIONAL register pipeline on the R11 single-buffer structure.
//    R7/R10 regressions shared one trait: CONDITIONAL prefetch (if kt<N) ->
//    divergent def-sites -> scratch. Now: load tile (kt+1)&7 every iteration
//    (wraps to tile 0, always in-bounds, branch-free, single def/use per reg).
//    Loads issue after barrier-2 and fly under the full compute phase.
//  proj: BK 64->128 (drains 16->8), inner loop over 4 K=32 chunks (register
//    pressure unchanged), swizzle re-derived for 16 units/row.
//  prep: R15/R17 form, frozen.

typedef __bf16 bf16;
typedef bf16 bf16x8 __attribute__((ext_vector_type(8)));
typedef bf16 bf16x4 __attribute__((ext_vector_type(4)));
typedef float floatx4 __attribute__((ext_vector_type(4)));
typedef float floatx16 __attribute__((ext_vector_type(16)));
typedef unsigned short ushort8 __attribute__((ext_vector_type(8)));
typedef unsigned long long u64;

#define MFMA32(A, B, C)    __builtin_amdgcn_mfma_f32_16x16x32_bf16((A), (B), (C), 0, 0, 0)
#define MFMA32x32(A, B, C) __builtin_amdgcn_mfma_f32_32x32x16_bf16((A), (B), (C), 0, 0, 0)

namespace {
constexpr int S   = 512;
constexpr int H   = 16;
constexpr int Dh  = 64;
constexpr int D   = 1024;
constexpr int LDT = 72;                          // padded LDS row stride (bf16)
constexpr size_t QN = (size_t)16 * S * H * Dh;   // 8,388,608
constexpr size_t WN = (size_t)D * D;             // 1,048,576
}

__device__ __forceinline__ float fexp2(float x) {
#if defined(__HIP_DEVICE_COMPILE__) && __has_builtin(__builtin_amdgcn_exp2f)
    return __builtin_amdgcn_exp2f(x);
#else
    return exp2f(x);
#endif
}

__device__ __forceinline__ int sbfe1(unsigned bits, int bit) {
    return ((int)(bits << (31 - bit))) >> 31;    // folds to v_bfe_i32
}

// Async global->LDS, 16B per lane. lds base must be wave-uniform (HW adds lane*16).
__device__ __forceinline__ void gload16(const bf16* g, bf16* ldsbase, int lane) {
#if __has_builtin(__builtin_amdgcn_global_load_lds)
    __builtin_amdgcn_global_load_lds(
        (__attribute__((address_space(1))) void*)(g),
        (__attribute__((address_space(3))) void*)(ldsbase), 16, 0, 0);
#else
    *(ushort8*)(ldsbase + lane * 8) = *(const ushort8*)g;   // host-pass / fallback
#endif
}

// Fused prep, grid 4352:
// [0,1024) K f32->bf16 x4 chunks | [1024,3072) V transpose | [3072,3328) W
// transpose | [3328,4352) mask bit-pack x4 units.
__global__ __launch_bounds__(256)
void prep_kernel(const float* __restrict__ Kf, const float* __restrict__ Vf,
                 const float* __restrict__ Wf, const int* __restrict__ Mg,
                 bf16* __restrict__ Kc, bf16* __restrict__ Vt,
                 bf16* __restrict__ Wt, u64* __restrict__ MB)
{
    __shared__ bf16 Ts[64 * LDT];
    const int blk = blockIdx.x, tid = threadIdx.x;

    if (blk < 1024) {                       // ---- K convert, 4 chunks/thread ----
        const int c0 = blk * 1024 + tid;    // chunk ids c0 + 256*k
        floatx4 f[4][2];
#pragma unroll
        for (int k = 0; k < 4; ++k) {
            const float* fs = Kf + (size_t)(c0 + k * 256) * 8;
            f[k][0] = *(const floatx4*)fs;
            f[k][1] = *(const floatx4*)(fs + 4);
        }
#pragma unroll
        for (int k = 0; k < 4; ++k) {
            bf16x8 v;
#pragma unroll
            for (int j = 0; j < 4; ++j) {
                v[j]     = (bf16)f[k][0][j];
                v[j + 4] = (bf16)f[k][1][j];
            }
            *(bf16x8*)(Kc + (size_t)(c0 + k * 256) * 8) = v;
        }
    } else if (blk < 3072) {                // ---- V [b][s][h][d] -> [(bh)][d][s] ----
        const int bk2 = blk - 1024;
        const int bh  = bk2 >> 3, st = bk2 & 7;
        const int b   = bh >> 4, h = bh & 15;
        const int r   = tid >> 2, c = (tid & 3) * 16;
        const float* src = Vf + ((size_t)((b * S + st * 64 + r) * H + h)) * Dh + c;
        floatx4 f0 = *(const floatx4*)src;          // vectorized: 4x dwordx4
        floatx4 f1 = *(const floatx4*)(src + 4);
        floatx4 f2 = *(const floatx4*)(src + 8);
        floatx4 f3 = *(const floatx4*)(src + 12);
        // element (d,s) stored at d*LDT + (s ^ (d&48)): write conflicts 8->2-way
#pragma unroll
        for (int i = 0; i < 4; ++i) {
            Ts[(c + i)      * LDT + (r ^ ((c + i)      & 48))] = (bf16)f0[i];
            Ts[(c + 4 + i)  * LDT + (r ^ ((c + 4 + i)  & 48))] = (bf16)f1[i];
            Ts[(c + 8 + i)  * LDT + (r ^ ((c + 8 + i)  & 48))] = (bf16)f2[i];
            Ts[(c + 12 + i) * LDT + (r ^ ((c + 12 + i) & 48))] = (bf16)f3[i];
        }
        __syncthreads();
        bf16* dst = Vt + ((size_t)bh * 64 + r) * S + st * 64 + c;
        const int rb = r * LDT + (c ^ (r & 48));
        *(ushort8*)dst       = *(const ushort8*)&Ts[rb];
        *(ushort8*)(dst + 8) = *(const ushort8*)&Ts[rb + 8];
    } else if (blk < 3328) {                // ---- W [k][n] -> [n][k] ----
        const int bk2 = blk - 3072;
        const int nb  = bk2 & 15, kb = bk2 >> 4;
        const int r   = tid >> 2, c = (tid & 3) * 16;
        const float* src = Wf + (size_t)(kb * 64 + r) * D + nb * 64 + c;
        floatx4 f0 = *(const floatx4*)src;          // vectorized: 4x dwordx4
        floatx4 f1 = *(const floatx4*)(src + 4);
        floatx4 f2 = *(const floatx4*)(src + 8);
        floatx4 f3 = *(const floatx4*)(src + 12);
#pragma unroll
        for (int i = 0; i < 4; ++i) {
            Ts[(c + i)      * LDT + (r ^ ((c + i)      & 48))] = (bf16)f0[i];
            Ts[(c + 4 + i)  * LDT + (r ^ ((c + 4 + i)  & 48))] = (bf16)f1[i];
            Ts[(c + 8 + i)  * LDT + (r ^ ((c + 8 + i)  & 48))] = (bf16)f2[i];
            Ts[(c + 12 + i) * LDT + (r ^ ((c + 12 + i) & 48))] = (bf16)f3[i];
        }
        __syncthreads();
        bf16* dst = Wt + (size_t)(nb * 64 + r) * D + kb * 64 + c;
        const int rb = r * LDT + (c ^ (r & 48));
        *(ushort8*)dst       = *(const ushort8*)&Ts[rb];
        *(ushort8*)(dst + 8) = *(const ushort8*)&Ts[rb + 8];
    } else {                                // ---- mask -> u64 bitmask, 4 units/wave ----
        const int bk2  = blk - 3328;        // [0,1024)
        const int lane = tid & 63;
        const int wv   = tid >> 6;
        const int u0   = bk2 * 16 + wv * 4; // idx4 base
        int mv[4][4];
#pragma unroll
        for (int u = 0; u < 4; ++u) {
            const int idx4 = u0 + u;
            const int row = idx4 >> 1, hf = idx4 & 1;
#pragma unroll
            for (int r = 0; r < 4; ++r)
                mv[u][r] = Mg[(size_t)row * 512 + hf * 256 + r * 64 + lane];
        }
#pragma unroll
        for (int u = 0; u < 4; ++u) {
            const int idx4 = u0 + u;
            const int row = idx4 >> 1, hf = idx4 & 1;
#pragma unroll
            for (int r = 0; r < 4; ++r) {
                u64 bm = __ballot(mv[u][r] != 0);
                if (lane == 0) MB[(size_t)row * 8 + hf * 4 + r] = bm;
            }
        }
    }
}

// One workgroup = one (b, h, 128-row q-tile). 4 waves x 32 q each (q = qw + l31).
// Single LDS buffer + UNCONDITIONAL register pipeline (tile (kt+1)&7).
// S^T and PV on mfma_f32_32x32x16_bf16; C/D: col=lane&31, row=(reg&3)+8*(reg>>2)+4*half.
__global__ __launch_bounds__(256, 4)
void attn_kernel(const float* __restrict__ Qg, const bf16* __restrict__ Kc,
                 const bf16* __restrict__ Vtg, const u64* __restrict__ MB,
                 bf16* __restrict__ heads)
{
    __shared__ bf16 Ks[64 * LDT];                 // rows PERMUTED: slot r = k-row swap23(r)
    __shared__ bf16 Vt[64 * LDT];                 // [d][s-in-tile], natural order

    const int tid  = threadIdx.x;
    const int lane = tid & 63;
    const int wave = tid >> 6;
    const int l31  = lane & 31;
    const int half = lane >> 5;

    const int blk = blockIdx.x;                   // ((b*4)+qt)*16 + h
    const int h   = blk & 15;
    const int qt  = (blk >> 4) & 3;
    const int b   = blk >> 6;
    const int qw  = qt * 128 + wave * 32;         // wave's q base; q = qw + l31

    // ---- Q B-frags: lane holds Q[qw+l31][ds*16 + half*8 + j] * 0.125*log2e ----
    constexpr float QSCL = 0.125f * 1.44269504088896340736f;
    bf16x8 aq[4];
    {
        const float* qb = Qg + ((size_t)((b * S + qw + l31) * H + h)) * Dh + half * 8;
#pragma unroll
        for (int ds = 0; ds < 4; ++ds) {
            floatx4 f0 = *(const floatx4*)(qb + ds * 16);
            floatx4 f1 = *(const floatx4*)(qb + ds * 16 + 4);
#pragma unroll
            for (int j = 0; j < 4; ++j) {
                aq[ds][j]     = (bf16)(f0[j] * QSCL);
                aq[ds][j + 4] = (bf16)(f1[j] * QSCL);
            }
        }
    }

    float rsum = 0.f;
    floatx16 O[2];                                // O^T[d = dt*32 + crow][q = l31]
#pragma unroll
    for (int dt = 0; dt < 2; ++dt)
#pragma unroll
        for (int i = 0; i < 16; ++i) O[dt][i] = 0.f;

    const u64* mbrow = MB + ((size_t)b * S + qw + l31) * 8;   // per-lane q row
    const bf16* vplane = Vtg + (size_t)(b * 16 + h) * 64 * S;

    const int sr = tid >> 2, sc_ = (tid & 3) * 16;            // 64x64 staging
    // swap bits 2<->3: staging slot r holds global k-row kperm so the S^T
    // C-tile lands P^T in 32x32x16 B-operand order (slot s*8+j <-> C reg s*8+j).
    const int kperm = (sr & 0x33) | ((sr & 4) << 1) | ((sr & 8) >> 1);

    const bf16* ksrc0 = Kc + ((size_t)((b * S + kperm) * H + h)) * Dh + sc_;
    const bf16* vsrc0 = vplane + (size_t)sr * S + sc_;
    const size_t kstep = (size_t)64 * H * Dh;

    // ---- prologue: tile 0 into regs (single def-site; no conditionals) ----
    ushort8 k0 = *(const ushort8*)ksrc0;
    ushort8 k1 = *(const ushort8*)(ksrc0 + 8);
    ushort8 v0 = *(const ushort8*)vsrc0;
    ushort8 v1 = *(const ushort8*)(vsrc0 + 8);
    u64 mreg = mbrow[0];

    for (int kt = 0; kt < 8; ++kt) {
        __syncthreads();                          // prev tile's LDS reads done
        *(ushort8*)&Ks[sr * LDT + sc_]     = k0;  // vmcnt satisfied long ago
        *(ushort8*)&Ks[sr * LDT + sc_ + 8] = k1;
        *(ushort8*)&Vt[sr * LDT + sc_]     = v0;
        *(ushort8*)&Vt[sr * LDT + sc_ + 8] = v1;
        const u64 m64 = mreg;
        __syncthreads();                          // LDS visible

        // ---- unconditional prefetch of tile (kt+1)&7 (wraps to 0: in-bounds,
        // branch-free). Latency hides under the compute below. ----
        {
            const int kn = (kt + 1) & 7;
            const bf16* ks = ksrc0 + (size_t)kn * kstep;
            const bf16* vs = vsrc0 + kn * 64;
            k0 = *(const ushort8*)ks;
            k1 = *(const ushort8*)(ks + 8);
            v0 = *(const ushort8*)vs;
            v1 = *(const ushort8*)(vs + 8);
            mreg = mbrow[kn];
        }

        // ---- S^T per 32-k tile t: C reg r holds k = t*32 + (r>>3)*16 + half*8 + (r&7) ----
        bf16x8 pB[4];                             // P^T B-operands, 16-k slice each
#pragma unroll
        for (int t = 0; t < 2; ++t) {
            floatx16 acc;
#pragma unroll
            for (int i = 0; i < 16; ++i) acc[i] = 0.f;
#pragma unroll
            for (int ds = 0; ds < 4; ++ds) {
                bf16x8 ak = *(const bf16x8*)&Ks[(t * 32 + l31) * LDT + ds * 16 + half * 8];
                acc = MFMA32x32(ak, aq[ds], acc);
            }
            const unsigned w = (unsigned)(m64 >> (t * 32 + half * 8));
#pragma unroll
            for (int r = 0; r < 16; ++r) {
                float e = fexp2(acc[r]);                    // v_exp_f32
                int sx = sbfe1(w, (r >> 3) * 16 + (r & 7)); // 0 or -1
                float p = __uint_as_float(__float_as_uint(e) & (unsigned)sx);
                rsum += p;
                pB[t * 2 + (r >> 3)][r & 7] = (bf16)p;
            }
        }

        // ---- O^T += V^T · P^T : A = Vt rows (natural), B = pB k-slices ----
#pragma unroll
        for (int dt = 0; dt < 2; ++dt)
#pragma unroll
            for (int s_ = 0; s_ < 4; ++s_) {
                bf16x8 av = *(const bf16x8*)&Vt[(dt * 32 + l31) * LDT + s_ * 16 + half * 8];
                O[dt] = MFMA32x32(av, pB[s_], O[dt]);
            }
    }

    // ---- reduce row sums: lanes l and l+32 share q = l31, disjoint k halves ----
    rsum += __shfl_xor(rsum, 32, 64);
    const float inv = (rsum > 0.f) ? (1.f / rsum) : 0.f;

    // ---- epilogue: O^T[d][q] -> heads[b][q][h][d]; d = dt*32 + g*8 + half*4 + j ----
    bf16* hrow = heads + ((size_t)((b * S + qw + l31) * H + h)) * Dh;
#pragma unroll
    for (int dt = 0; dt < 2; ++dt) {
#pragma unroll
        for (int g = 0; g < 4; ++g) {
            bf16x4 h4;
#pragma unroll
            for (int j = 0; j < 4; ++j) h4[j] = (bf16)(O[dt][g * 4 + j] * inv);
            *(bf16x4*)&hrow[dt * 32 + g * 8 + half * 4] = h4;
        }
    }
}

// Projection: heads (8192x1024) @ Wt^T. 128x128 tile, BK=128 (8 K-steps,
// drains halved), LDS linear for global_load_lds with PRE-SWIZZLED global
// source (rule 21): 16B unit (row, u) stored at phys u ^ (row&7); reads
// re-apply the XOR. Inner loop over 4 K=32 chunks keeps register pressure
// at the BK=64 level.
__global__ __launch_bounds__(256)
void proj_kernel(const bf16* __restrict__ A, const bf16* __restrict__ Wt,
                 float* __restrict__ out)
{
    __shared__ bf16 As[128 * 128];                // 32 KB, linear
    __shared__ bf16 Ws[128 * 128];                // 32 KB, linear

    const int tid  = threadIdx.x;
    const int lane = tid & 63;
    const int wave = tid >> 6;
    const int l15  = lane & 15;
    const int quad = lane >> 4;

    const int nb = blockIdx.x & 7;
    const int mb = blockIdx.x >> 3;
    const int mbase = mb * 128, nbase = nb * 128;
    const int wm = (wave & 1) * 64, wn = (wave >> 1) * 64;

    // staging: per issue, 4 rows x 16 units (1 KB). lane -> (srow4 = lane>>4,
    // unit su = lane&15); global col unit pre-swizzled: su ^ (row&7).
    const int srow4 = lane >> 4;                  // 0..3
    const int su    = lane & 15;

    floatx4 O[4][4];
#pragma unroll
    for (int mt = 0; mt < 4; ++mt)
#pragma unroll
        for (int nt = 0; nt < 4; ++nt) O[mt][nt] = floatx4{0.f, 0.f, 0.f, 0.f};

    for (int kt = 0; kt < 8; ++kt) {
        const int kb = kt * 128;
        if (kt) __syncthreads();                  // prev compute done; LDS free

#pragma unroll
        for (int j = 0; j < 8; ++j) {
            const int rowbase = wave * 32 + j * 4;
            const int cu = (su ^ ((rowbase + srow4) & 7)) * 8;
            gload16(A  + (size_t)(mbase + rowbase + srow4) * D + kb + cu,
                    As + rowbase * 128, lane);
            gload16(Wt + (size_t)(nbase + rowbase + srow4) * D + kb + cu,
                    Ws + rowbase * 128, lane);
        }

        __syncthreads();                          // vmcnt drained -> LDS visible

#pragma unroll
        for (int c = 0; c < 4; ++c) {
            const int uc = c * 4 + quad;          // logical 16B unit (K chunk c)
            bf16x8 fa[4];
#pragma unroll
            for (int mt = 0; mt < 4; ++mt) {
                const int row = wm + mt * 16 + l15;
                fa[mt] = *(const bf16x8*)&As[row * 128 + ((uc ^ (row & 7)) * 8)];
            }
#pragma unroll
            for (int nt = 0; nt < 4; ++nt) {
                const int row = wn + nt * 16 + l15;
                bf16x8 fb = *(const bf16x8*)&Ws[row * 128 + ((uc ^ (row & 7)) * 8)];
#pragma unroll
                for (int mt = 0; mt < 4; ++mt)
                    O[mt][nt] = MFMA32(fa[mt], fb, O[mt][nt]);
            }
        }
    }

#pragma unroll
    for (int mt = 0; mt < 4; ++mt) {
#pragma unroll
        for (int nt = 0; nt < 4; ++nt) {
#pragma unroll
            for (int reg = 0; reg < 4; ++reg) {
                const int m = mbase + wm + mt * 16 + quad * 4 + reg;
                const int n = nbase + wn + nt * 16 + l15;
                out[(size_t)m * D + n] = O[mt][nt][reg];
            }
        }
    }
}

extern "C" void kernel_launch(void* const* d_in, const int* in_sizes, int n_in,
                              void* d_out, int out_size, void* d_ws, size_t ws_size,
                              hipStream_t stream)
{
    const float* pre_q = (const float*)d_in[0];
    const float* pre_v = (const float*)d_in[1];
    const float* pre_k = (const float*)d_in[2];
    const int*   mask  = (const int*)d_in[3];
    const float* Wg    = (const float*)d_in[4];
    float* out = (float*)d_out;

    bf16* Kc    = (bf16*)d_ws;
    bf16* Vt    = Kc + QN;
    bf16* Wt    = Vt + QN;
    bf16* heads = Wt + WN;
    u64*  MB    = (u64*)(heads + QN);

    prep_kernel<<<4352, 256, 0, stream>>>(pre_k, pre_v, Wg, mask, Kc, Vt, Wt, MB);
    attn_kernel<<<1024, 256, 0, stream>>>(pre_q, Kc, Vt, MB, heads);
    proj_kernel<<<512, 256, 0, stream>>>(heads, Wt, out);
}